// Round 4
// baseline (2072.468 us; speedup 1.0000x reference)
//
#include <hip/hip_runtime.h>
#include <stdint.h>

#define MROWS  200704
#define SCALE_ 0.17677669529663687f  // 32^-0.5

typedef __attribute__((ext_vector_type(8))) short bf16x8;
typedef __attribute__((ext_vector_type(4))) float f32x4;
union V8 { uint4 u; unsigned short s[8]; };

__device__ __forceinline__ float bf2f(unsigned short u) {
  union { unsigned int i; float f; } c; c.i = ((unsigned int)u) << 16; return c.f;
}
__device__ __forceinline__ unsigned short f2bf(float f) {
  union { float f; unsigned int i; } c; c.f = f;
  unsigned int lsb = (c.i >> 16) & 1;
  return (unsigned short)((c.i + 0x7fffu + lsb) >> 16);
}

// ---- async global->LDS, 16B per lane, wave-uniform LDS base ----
typedef __attribute__((address_space(1))) const void gas_t;
typedef __attribute__((address_space(3))) void las_t;
__device__ __forceinline__ void gload16(const void* g, void* l) {
  __builtin_amdgcn_global_load_lds((gas_t*)g, (las_t*)l, 16, 0, 0);
}

// ---- swizzled A-tile (128 rows x 192 bf16, linear 48KB LDS) ----
// LDS chunk (row, c) holds data chunk (row, c ^ (row&7)); chunks are 8 bf16 (16B).
// Read of logical k (multiple of 8):
__device__ __forceinline__ bf16x8 ard(const unsigned short* As, int row, int k) {
  return *reinterpret_cast<const bf16x8*>(As + row * 192 + (((k >> 3) ^ (row & 7)) << 3));
}
__device__ __forceinline__ void awr(unsigned short* As, int row, int c, unsigned short v) {
  As[row * 192 + (((c >> 3) ^ (row & 7)) << 3) + (c & 7)] = v;
}
// stage 128x192 bf16 tile from global (row stride RS elems, col offset colofs) via global_load_lds
template<int RS>
__device__ __forceinline__ void stage_a(const unsigned short* __restrict__ src,
                                        unsigned short* As, int wv, int lane, int colofs) {
  #pragma unroll
  for (int i = 0; i < 12; ++i) {
    int g = wv * 768 + i * 64 + lane;      // chunk id 0..3071
    int row = g / 24, c = g - row * 24;
    int sc = c ^ (row & 7);
    gload16(src + (size_t)row * RS + colofs + sc * 8, As + (wv * 768 + i * 64) * 8);
  }
}
// LN one row (all 64 lanes) -> swizzled LDS bf16
__device__ __forceinline__ void ln_row(const float* __restrict__ xr,
    const float* __restrict__ g, const float* __restrict__ b,
    unsigned short* As, int row, int lane) {
  float v0 = xr[lane], v1 = xr[lane + 64], v2 = xr[lane + 128];
  float s  = v0 + v1 + v2;
  float s2 = v0*v0 + v1*v1 + v2*v2;
  #pragma unroll
  for (int m = 32; m >= 1; m >>= 1) { s += __shfl_xor(s, m); s2 += __shfl_xor(s2, m); }
  float mean = s * (1.0f/192.0f);
  float var  = s2 * (1.0f/192.0f) - mean*mean;
  float inv  = rsqrtf(var + 1e-5f);
  awr(As, row, lane,       f2bf((v0-mean)*inv*g[lane]      + b[lane]));
  awr(As, row, lane+64,    f2bf((v1-mean)*inv*g[lane+64]   + b[lane+64]));
  awr(As, row, lane+128,   f2bf((v2-mean)*inv*g[lane+128]  + b[lane+128]));
}
// one 64-col panel: acc += A(128x192) * Wt-panel; afr pre-hoisted
__device__ __forceinline__ void panel_mm(const bf16x8 (&afr)[6][4],
    const unsigned short* __restrict__ Wp, int kq, f32x4 (&acc)[4][2]) {
  bf16x8 bfr[6][2];
  #pragma unroll
  for (int ks = 0; ks < 6; ++ks) {
    bfr[ks][0] = *reinterpret_cast<const bf16x8*>(Wp + ks*32 + kq);
    bfr[ks][1] = *reinterpret_cast<const bf16x8*>(Wp + 16*192 + ks*32 + kq);
  }
  #pragma unroll
  for (int ks = 0; ks < 6; ++ks)
    #pragma unroll
    for (int mi = 0; mi < 4; ++mi) {
      acc[mi][0] = __builtin_amdgcn_mfma_f32_16x16x32_bf16(afr[ks][mi], bfr[ks][0], acc[mi][0], 0, 0, 0);
      acc[mi][1] = __builtin_amdgcn_mfma_f32_16x16x32_bf16(afr[ks][mi], bfr[ks][1], acc[mi][1], 0, 0, 0);
    }
}

// ---------------- weight convert+transpose ----------------
__global__ __launch_bounds__(256) void wt_k(const float* __restrict__ W,
    unsigned short* __restrict__ Wt, int K, int N)
{
  int idx = blockIdx.x * 256 + threadIdx.x;
  if (idx < K * N) {
    int k = idx / N, n = idx - k * N;
    Wt[(size_t)n * K + k] = f2bf(W[idx]);
  }
}

// ---------------- fused LN1(windowed gather) + QKV GEMM ----------------
__global__ __launch_bounds__(256, 2) void qkv_k(const float* __restrict__ X,
    const float* __restrict__ g, const float* __restrict__ b,
    const unsigned short* __restrict__ Wt, const float* __restrict__ bias,
    unsigned short* __restrict__ C, int shift)
{
  __shared__ unsigned short As[128 * 192];
  const int tid = threadIdx.x, lane = tid & 63, wv = tid >> 6;
  const int row0 = blockIdx.x * 128;
  #pragma unroll 2
  for (int r = 0; r < 32; ++r) {
    int row = wv * 32 + r, wr = row0 + row;
    int win = wr / 49, n = wr - win * 49;
    int bi = win >> 6, w64 = win & 63, wh = w64 >> 3, ww = w64 & 7;
    int ti = n / 7, tj = n - ti * 7;
    int gh = wh*7 + ti + shift; if (gh >= 56) gh -= 56;
    int gw = ww*7 + tj + shift; if (gw >= 56) gw -= 56;
    ln_row(X + ((size_t)bi*3136 + gh*56 + gw)*192, g, b, As, row, lane);
  }
  __syncthreads();
  const int wm = wv >> 1, wn = wv & 1, fr = lane & 15, kq = (lane >> 4) * 8;
  bf16x8 afr[6][4];
  #pragma unroll
  for (int ks = 0; ks < 6; ++ks)
    #pragma unroll
    for (int mi = 0; mi < 4; ++mi)
      afr[ks][mi] = ard(As, wm*64 + mi*16 + fr, ks*32 + kq);
  const int lcol = lane & 15, lr4 = (lane >> 4) * 4;
  #pragma unroll 2
  for (int p = 0; p < 9; ++p) {
    f32x4 acc[4][2] = {};
    panel_mm(afr, Wt + (size_t)(p*64 + wn*32 + fr) * 192, kq, acc);
    #pragma unroll
    for (int mi = 0; mi < 4; ++mi)
    #pragma unroll
    for (int ni = 0; ni < 2; ++ni)
    #pragma unroll
    for (int i = 0; i < 4; ++i) {
      int gr = row0 + wm*64 + mi*16 + lr4 + i;
      int gc = p*64 + wn*32 + ni*16 + lcol;
      C[(size_t)gr * 576 + gc] = f2bf(acc[mi][ni][i] + bias[gc]);
    }
  }
}

// ---------------- proj GEMM + window-reverse scatter residual ----------------
__global__ __launch_bounds__(256, 2) void proj_k(const unsigned short* __restrict__ A,
    const unsigned short* __restrict__ Wt, const float* __restrict__ bias,
    const float* __restrict__ Xres, float* __restrict__ Xdst, int shift)
{
  __shared__ unsigned short As[128 * 192];
  const int tid = threadIdx.x, lane = tid & 63, wv = tid >> 6;
  const int row0 = blockIdx.x * 128;
  stage_a<192>(A + (size_t)row0 * 192, As, wv, lane, 0);
  __syncthreads();
  const int wm = wv >> 1, wn = wv & 1, fr = lane & 15, kq = (lane >> 4) * 8;
  bf16x8 afr[6][4];
  #pragma unroll
  for (int ks = 0; ks < 6; ++ks)
    #pragma unroll
    for (int mi = 0; mi < 4; ++mi)
      afr[ks][mi] = ard(As, wm*64 + mi*16 + fr, ks*32 + kq);
  const int lcol = lane & 15, lr4 = (lane >> 4) * 4;
  int rbase[16];
  #pragma unroll
  for (int mi = 0; mi < 4; ++mi)
  #pragma unroll
  for (int i = 0; i < 4; ++i) {
    int gr = row0 + wm*64 + mi*16 + lr4 + i;
    int win = gr / 49, n = gr - win * 49;
    int bi = win >> 6, w64 = win & 63, wh = w64 >> 3, ww = w64 & 7;
    int ti = n / 7, tj = n - ti * 7;
    int gh = wh*7 + ti + shift; if (gh >= 56) gh -= 56;
    int gw = ww*7 + tj + shift; if (gw >= 56) gw -= 56;
    rbase[mi*4 + i] = (bi*3136 + gh*56 + gw) * 192;
  }
  #pragma unroll
  for (int p = 0; p < 3; ++p) {
    f32x4 acc[4][2] = {};
    panel_mm(afr, Wt + (size_t)(p*64 + wn*32 + fr) * 192, kq, acc);
    #pragma unroll
    for (int mi = 0; mi < 4; ++mi)
    #pragma unroll
    for (int ni = 0; ni < 2; ++ni)
    #pragma unroll
    for (int i = 0; i < 4; ++i) {
      int gc = p*64 + wn*32 + ni*16 + lcol;
      size_t idx = (size_t)rbase[mi*4 + i] + gc;
      Xdst[idx] = Xres[idx] + acc[mi][ni][i] + bias[gc];
    }
  }
}

// ---------------- fused LN2 + FC1 + GELU ----------------
__global__ __launch_bounds__(256, 2) void fc1_k(const float* __restrict__ X,
    const float* __restrict__ g, const float* __restrict__ b,
    const unsigned short* __restrict__ Wt, const float* __restrict__ bias,
    unsigned short* __restrict__ H)
{
  __shared__ unsigned short As[128 * 192];
  const int tid = threadIdx.x, lane = tid & 63, wv = tid >> 6;
  const int row0 = blockIdx.x * 128;
  #pragma unroll 2
  for (int r = 0; r < 32; ++r) {
    int row = wv * 32 + r;
    ln_row(X + (size_t)(row0 + row) * 192, g, b, As, row, lane);
  }
  __syncthreads();
  const int wm = wv >> 1, wn = wv & 1, fr = lane & 15, kq = (lane >> 4) * 8;
  bf16x8 afr[6][4];
  #pragma unroll
  for (int ks = 0; ks < 6; ++ks)
    #pragma unroll
    for (int mi = 0; mi < 4; ++mi)
      afr[ks][mi] = ard(As, wm*64 + mi*16 + fr, ks*32 + kq);
  const int lcol = lane & 15, lr4 = (lane >> 4) * 4;
  #pragma unroll 2
  for (int p = 0; p < 12; ++p) {
    f32x4 acc[4][2] = {};
    panel_mm(afr, Wt + (size_t)(p*64 + wn*32 + fr) * 192, kq, acc);
    #pragma unroll
    for (int mi = 0; mi < 4; ++mi)
    #pragma unroll
    for (int ni = 0; ni < 2; ++ni)
    #pragma unroll
    for (int i = 0; i < 4; ++i) {
      int gr = row0 + wm*64 + mi*16 + lr4 + i;
      int gc = p*64 + wn*32 + ni*16 + lcol;
      float v = acc[mi][ni][i] + bias[gc];
      float gv = 0.5f * v * (1.0f + erff(v * 0.70710678118654752f));
      H[(size_t)gr * 768 + gc] = f2bf(gv);
    }
  }
}

// ---------------- FC2 (K=768, 4 staged quarters) + residual ----------------
__global__ __launch_bounds__(256, 2) void fc2_k(const unsigned short* __restrict__ H,
    const unsigned short* __restrict__ Wt,   // [192][768]
    const float* __restrict__ bias, const float* __restrict__ Xres,
    float* __restrict__ Y)
{
  __shared__ unsigned short As[128 * 192];
  const int tid = threadIdx.x, lane = tid & 63, wv = tid >> 6;
  const int row0 = blockIdx.x * 128;
  const int wm = wv >> 1, wn = wv & 1, fr = lane & 15, kq = (lane >> 4) * 8;
  f32x4 acc[3][4][2] = {};
  for (int q = 0; q < 4; ++q) {
    if (q) __syncthreads();                  // all waves done reading prev quarter
    stage_a<768>(H + (size_t)row0 * 768, As, wv, lane, q * 192);
    __syncthreads();
    #pragma unroll
    for (int ks = 0; ks < 6; ++ks) {
      bf16x8 afr[4];
      #pragma unroll
      for (int mi = 0; mi < 4; ++mi)
        afr[mi] = ard(As, wm*64 + mi*16 + fr, ks*32 + kq);
      #pragma unroll
      for (int p = 0; p < 3; ++p) {
        const unsigned short* wp = Wt + (size_t)(p*64 + wn*32 + fr) * 768 + q*192 + ks*32 + kq;
        bf16x8 b0 = *reinterpret_cast<const bf16x8*>(wp);
        bf16x8 b1 = *reinterpret_cast<const bf16x8*>(wp + 16*768);
        #pragma unroll
        for (int mi = 0; mi < 4; ++mi) {
          acc[p][mi][0] = __builtin_amdgcn_mfma_f32_16x16x32_bf16(afr[mi], b0, acc[p][mi][0], 0, 0, 0);
          acc[p][mi][1] = __builtin_amdgcn_mfma_f32_16x16x32_bf16(afr[mi], b1, acc[p][mi][1], 0, 0, 0);
        }
      }
    }
  }
  const int lcol = lane & 15, lr4 = (lane >> 4) * 4;
  #pragma unroll
  for (int p = 0; p < 3; ++p)
  #pragma unroll
  for (int mi = 0; mi < 4; ++mi)
  #pragma unroll
  for (int ni = 0; ni < 2; ++ni)
  #pragma unroll
  for (int i = 0; i < 4; ++i) {
    int grow = row0 + wm*64 + mi*16 + lr4 + i;
    int gc = p*64 + wn*32 + ni*16 + lcol;
    float v = acc[p][mi][ni][i] + bias[gc];
    size_t idx = (size_t)grow * 192 + gc;
    Y[idx] = Xres[idx] + v;
  }
}

// ---------------- Windowed attention: one wave per (window, head) ----------------
template<bool SHIFTED>
__global__ __launch_bounds__(64) void attn_k(
    const unsigned short* __restrict__ qkv,
    const float* __restrict__ rpb,
    unsigned short* __restrict__ out)
{
  __shared__ float kv[2][49][32];
  int blk = blockIdx.x;
  int win = blk / 6, h = blk - win * 6;
  int lane = threadIdx.x;
  const unsigned short* base = qkv + (size_t)win * 49 * 576;
  for (int idx = lane; idx < 196; idx += 64) {
    int n = idx >> 2, sg = (idx & 3) * 8;
    V8 kk, vv;
    kk.u = *reinterpret_cast<const uint4*>(base + n*576 + 192 + h*32 + sg);
    vv.u = *reinterpret_cast<const uint4*>(base + n*576 + 384 + h*32 + sg);
    #pragma unroll
    for (int j = 0; j < 8; ++j) { kv[0][n][sg+j] = bf2f(kk.s[j]); kv[1][n][sg+j] = bf2f(vv.s[j]); }
  }
  __syncthreads();
  if (lane < 49) {
    float q[32];
    const unsigned short* qr = base + (size_t)lane * 576 + h * 32;
    #pragma unroll
    for (int sg = 0; sg < 4; ++sg) {
      V8 qq; qq.u = *reinterpret_cast<const uint4*>(qr + sg*8);
      #pragma unroll
      for (int j = 0; j < 8; ++j) q[sg*8+j] = bf2f(qq.s[j]) * SCALE_;
    }
    int ti = lane / 7, tj = lane - ti * 7;
    int wi = win & 63, wh = wi >> 3, ww = wi & 7;
    int rid = 0;
    if (SHIFTED) {
      int hh = wh*7 + ti, wg = ww*7 + tj;
      rid = (hh < 49 ? 0 : (hh < 53 ? 1 : 2)) * 3 + (wg < 49 ? 0 : (wg < 53 ? 1 : 2));
    }
    float s[49];
    float mx = -1e30f;
    #pragma unroll
    for (int m = 0; m < 49; ++m) {
      float a = 0.f;
      #pragma unroll
      for (int d4 = 0; d4 < 8; ++d4) {
        float4 kf = *reinterpret_cast<const float4*>(&kv[0][m][d4*4]);
        a += q[d4*4+0]*kf.x + q[d4*4+1]*kf.y + q[d4*4+2]*kf.z + q[d4*4+3]*kf.w;
      }
      int mi = m / 7, mj = m - mi * 7;
      a += rpb[((ti - mi + 6) * 13 + (tj - mj + 6)) * 6 + h];
      if (SHIFTED) {
        int hh = wh*7 + mi, wg = ww*7 + mj;
        int rid2 = (hh < 49 ? 0 : (hh < 53 ? 1 : 2)) * 3 + (wg < 49 ? 0 : (wg < 53 ? 1 : 2));
        if (rid2 != rid) a -= 100.f;
      }
      s[m] = a;
      mx = fmaxf(mx, a);
    }
    float sum = 0.f;
    #pragma unroll
    for (int m = 0; m < 49; ++m) { float e = __expf(s[m] - mx); s[m] = e; sum += e; }
    float rs = 1.f / sum;
    float o[32];
    #pragma unroll
    for (int d = 0; d < 32; ++d) o[d] = 0.f;
    #pragma unroll
    for (int m = 0; m < 49; ++m) {
      float p = s[m] * rs;
      #pragma unroll
      for (int d4 = 0; d4 < 8; ++d4) {
        float4 vf = *reinterpret_cast<const float4*>(&kv[1][m][d4*4]);
        o[d4*4+0] += p*vf.x; o[d4*4+1] += p*vf.y; o[d4*4+2] += p*vf.z; o[d4*4+3] += p*vf.w;
      }
    }
    unsigned short* orow = out + ((size_t)win * 49 + lane) * 192 + h * 32;
    #pragma unroll
    for (int sg = 0; sg < 4; ++sg) {
      V8 pk;
      #pragma unroll
      for (int j = 0; j < 8; ++j) pk.s[j] = f2bf(o[sg*8+j]);
      *reinterpret_cast<uint4*>(orow + sg*8) = pk.u;
    }
  }
}

// ---------------- launch ----------------
extern "C" void kernel_launch(void* const* d_in, const int* in_sizes, int n_in,
                              void* d_out, int out_size, void* d_ws, size_t ws_size,
                              hipStream_t stream) {
  const float* x    = (const float*)d_in[0];
  const float* n1g  = (const float*)d_in[1];
  const float* n1b  = (const float*)d_in[2];
  const float* qkvw = (const float*)d_in[3];
  const float* qkvb = (const float*)d_in[4];
  const float* rpb  = (const float*)d_in[5];
  const float* pw   = (const float*)d_in[6];
  const float* pb   = (const float*)d_in[7];
  const float* n2g  = (const float*)d_in[8];
  const float* n2b  = (const float*)d_in[9];
  const float* f1w  = (const float*)d_in[10];
  const float* f1b  = (const float*)d_in[11];
  const float* f2w  = (const float*)d_in[12];
  const float* f2b  = (const float*)d_in[13];
  float* out = (float*)d_out;

  // ws: x1 fp32 | Bbuf bf16 (576col) | Abuf bf16 (192col) | WT
  // Hbuf (768col) overlays Bbuf+Abuf exactly (231.2 + 77.1 = 308.3 MB).
  const size_t XBYTES = (size_t)MROWS * 192 * 4;
  const size_t QBYTES = (size_t)MROWS * 576 * 2;
  const size_t ABYTES = (size_t)MROWS * 192 * 2;
  char* ws = (char*)d_ws;
  float* x1 = (float*)ws;
  unsigned short* Bbuf = (unsigned short*)(ws + XBYTES);
  unsigned short* Abuf = (unsigned short*)(ws + XBYTES + QBYTES);
  unsigned short* Hbuf = Bbuf;
  unsigned short* WT   = (unsigned short*)(ws + XBYTES + QBYTES + ABYTES);
  const size_t WQ = 110592, WP = 36864, W1 = 147456, W2 = 147456;
  const size_t WD = WQ + WP + W1 + W2;

  for (int d = 0; d < 2; ++d) {
    unsigned short* wt = WT + d * WD;
    wt_k<<<(int)((WQ + 255)/256), 256, 0, stream>>>(qkvw + (size_t)d*WQ, wt,                 192, 576);
    wt_k<<<(int)((WP + 255)/256), 256, 0, stream>>>(pw   + (size_t)d*WP, wt + WQ,            192, 192);
    wt_k<<<(int)((W1 + 255)/256), 256, 0, stream>>>(f1w  + (size_t)d*W1, wt + WQ + WP,       192, 768);
    wt_k<<<(int)((W2 + 255)/256), 256, 0, stream>>>(f2w  + (size_t)d*W2, wt + WQ + WP + W1,  768, 192);
  }

  const int GB = MROWS / 128;   // 1568

  for (int i = 0; i < 2; ++i) {
    int shift = i ? 3 : 0;
    const float* xin = i ? (const float*)x1 : x;
    float* xfin = i ? out : x1;
    const unsigned short* wt = WT + i * WD;
    // 1. LN1 + gather + QKV gemm -> Bbuf
    qkv_k<<<GB, 256, 0, stream>>>(xin, n1g + i*192, n1b + i*192, wt, qkvb + i*576, Bbuf, shift);
    // 2. attention -> Abuf
    if (shift) attn_k<true ><<<4096*6, 64, 0, stream>>>(Bbuf, rpb + i*169*6, Abuf);
    else       attn_k<false><<<4096*6, 64, 0, stream>>>(Bbuf, rpb + i*169*6, Abuf);
    // 3. proj gemm + window-reverse scatter residual -> x1
    proj_k<<<GB, 256, 0, stream>>>(Abuf, wt + WQ, pb + i*192, xin, x1, shift);
    // 4. LN2 + FC1 + GELU -> Hbuf (overlays Bbuf/Abuf, both dead)
    fc1_k<<<GB, 256, 0, stream>>>(x1, n2g + i*192, n2b + i*192, wt + WQ + WP, f1b + i*768, Hbuf);
    // 5. FC2 + residual -> x1 / out
    fc2_k<<<GB, 256, 0, stream>>>(Hbuf, wt + WQ + WP + W1, f2b + i*192, x1, xfin);
  }
}